// Round 4
// baseline (291.659 us; speedup 1.0000x reference)
//
#include <hip/hip_runtime.h>
#include <hip/hip_bf16.h>
#include <math.h>

// Problem dims (fixed by reference)
#define BB 8
#define SS 8192
#define AGG_OUT 224   // D - DV

// ---- workspace layout (float/int32 slots, 4B each) ----
#define WS_FLAGS 0       // [0]=floatmode(1=bf16,0=f32) [1]=maskmode(0=i32,1=f32,2=bf16,3=u8)
#define WS_M     16      // (v*8+h)*12 + i*3+j : bilinear score matrices (log2e-prescaled); 6144
#define WS_AV3   6160    // AV[256], CV[256], DV[256] (DV includes bv)
#define WS_WVE   6928    // var_emb @ wv[0:32,:]  [64*256]
#define WS_SP    23312   // [64 sblk * 64 v * 8] stats partials {cnt,sv,st,vmnK,vmxK,tmnK,tmxK,pad}
#define WS_BINS  56080   // [8b*64v*24] v*24 + h*3 + {W,WV,WT}  (zeroed in K1)

__device__ __forceinline__ float ldf(const void* p, int idx, int fm) {
  if (fm) {
    unsigned int u = ((const unsigned short*)p)[idx];
    return __uint_as_float(u << 16);
  }
  return ((const float*)p)[idx];
}

__device__ __forceinline__ bool mask_at(const void* p, int idx, int mm) {
  switch (mm) {
    case 0: return ((const int*)p)[idx] != 0;
    case 1: return ((const float*)p)[idx] != 0.0f;
    case 2: return ((const unsigned short*)p)[idx] != 0;
    default: return ((const unsigned char*)p)[idx] != 0;
  }
}

// order-preserving float<->uint key (for atomicMin/Max on LDS uints)
__device__ __forceinline__ unsigned int fkey(float f) {
  unsigned int u = __float_as_uint(f);
  return (u & 0x80000000u) ? ~u : (u | 0x80000000u);
}
__device__ __forceinline__ float funkey(unsigned int k) {
  unsigned int u = (k & 0x80000000u) ? (k ^ 0x80000000u) : ~k;
  return __uint_as_float(u);
}

__device__ __forceinline__ int detect_fm_block(const void* times) {
  __shared__ int cntR;
  int tid = threadIdx.x;
  if (tid == 0) cntR = 0;
  __syncthreads();
  const unsigned int* tw = (const unsigned int*)times;
  int local = 0;
  for (int i = tid; i < 1024; i += 256) {
    unsigned int lo = tw[i] & 0xFFFFu;
    if (lo >= 0x3800u && lo < 0x3F80u) local++;   // bf16 pattern of U(0,1)
  }
  atomicAdd(&cntR, local);
  __syncthreads();
  int r = (cntR > 512) ? 1 : 0;
  __syncthreads();
  return r;
}

__device__ __forceinline__ int detect_mm_block(const void* mask) {
  __shared__ int f01, ff32, fbf;
  int tid = threadIdx.x;
  if (tid == 0) { f01 = 1; ff32 = 1; fbf = 1; }
  __syncthreads();
  const unsigned int* mw = (const unsigned int*)mask;
  int l01 = 1, lf32 = 1, lbf = 1;
  for (int i = tid; i < 2048; i += 256) {
    unsigned int w = mw[i];
    if (w > 1u) l01 = 0;
    if (!(w == 0u || w == 0x3F800000u)) lf32 = 0;
    unsigned int h0 = w & 0xFFFFu, h1 = w >> 16;
    if (!((h0 == 0u || h0 == 0x3F80u) && (h1 == 0u || h1 == 0x3F80u))) lbf = 0;
  }
  if (!l01) atomicAnd(&f01, 0);
  if (!lf32) atomicAnd(&ff32, 0);
  if (!lbf) atomicAnd(&fbf, 0);
  __syncthreads();
  int r = f01 ? 0 : (ff32 ? 1 : (fbf ? 2 : 3));
  __syncthreads();
  return r;
}

// K1: blocks 0..63: per-v M(v,h) bilinear matrices + WVE row (+ v<8: AV/CV/DV slice);
//     blocks 64..127: per-(b,chunk) segment stats histograms;
//     blocks 128..135: zero BINS (blk 128 publishes flags).
__global__ void __launch_bounds__(256) k_front(const void* times, const void* values,
                                               const int* fids, const void* mask,
                                               const void* me_w, const void* me_b,
                                               const void* time_w, const void* time_b,
                                               const void* agg_w, const void* agg_b,
                                               const void* var_emb, const void* wq,
                                               const void* wk, const void* wv,
                                               const void* bq, const void* bv,
                                               float* ws) {
  int blk = blockIdx.x, tid = threadIdx.x;
  if (blk < 64) {
    int fm = detect_fm_block(times);
    int v = blk;
    // stage 1: acd collapse (a[j],c[j],d[j]): h_l[:,32+j] = val*a + tim*c + d
    __shared__ float a_[224], c_[224], d_[224];
    if (tid < 224) {
      float sa = 0.f, sc = 0.f, sd = 0.f;
      for (int i = 0; i < 256; i++) {
        float w0 = ldf(agg_w, i * AGG_OUT + tid, fm);
        float w1 = ldf(agg_w, (256 + i) * AGG_OUT + tid, fm);
        sa += ldf(me_w, i, fm) * w0;
        sc += ldf(time_w, i, fm) * w1;
        sd += ldf(me_b, i, fm) * w0 + ldf(time_b, i, fm) * w1;
      }
      a_[tid] = sa; c_[tid] = sc; d_[tid] = sd + ldf(agg_b, tid, fm);
    }
    __syncthreads();
    // stage 2: fold through wq, wk (thread = d)
    int d = tid;
    float AQ = 0.f, CQ = 0.f, DQ = 0.f, AK = 0.f, CK = 0.f, DK = 0.f;
    for (int j = 0; j < 224; j++) {
      float wwq = ldf(wq, (32 + j) * 256 + d, fm);
      float wwk = ldf(wk, (32 + j) * 256 + d, fm);
      float aj = a_[j], cj = c_[j], dj = d_[j];
      AQ += aj * wwq; CQ += cj * wwq; DQ += dj * wwq;
      AK += aj * wwk; CK += cj * wwk; DK += dj * wwk;
    }
    // stage 3: embedding rows for own v
    float QE = 0.f, KE = 0.f, VE = 0.f;
    for (int i = 0; i < 32; i++) {
      float ve = ldf(var_emb, v * 32 + i, fm);
      QE += ve * ldf(wq, i * 256 + d, fm);
      KE += ve * ldf(wk, i * 256 + d, fm);
      VE += ve * ldf(wv, i * 256 + d, fm);
    }
    ws[WS_WVE + v * 256 + d] = VE;
    // stage 4: M(v,h)[i][j] = sum_d q_i[d]*k_j[d] over head h's 32 dims
    float q0 = ldf(bq, d, fm) + QE + DQ, k0 = KE + DK;
    float mm_[9] = {q0 * k0, q0 * AK, q0 * CK,
                    AQ * k0, AQ * AK, AQ * CK,
                    CQ * k0, CQ * AK, CQ * CK};
    #pragma unroll
    for (int r = 0; r < 9; r++)
      #pragma unroll
      for (int off = 16; off >= 1; off >>= 1)
        mm_[r] += __shfl_xor(mm_[r], off);
    if ((tid & 31) == 0) {
      int h = tid >> 5;
      const float sc2 = 0.17677669529663687f * 1.4426950408889634f; // 1/sqrt(32)*log2e
      int base = WS_M + (v * 8 + h) * 12;
      #pragma unroll
      for (int r = 0; r < 9; r++) ws[base + r] = mm_[r] * sc2;
    }
    // stage 5 (v<8): value-side fold slice AV/CV/DV for d2 in [v*32, v*32+32)
    if (v < 8) {
      int dsub = tid & 31, jg = tid >> 5;
      int d2 = v * 32 + dsub;
      float sa = 0.f, sc3 = 0.f, sd = 0.f;
      #pragma unroll 4
      for (int jj = 0; jj < 28; jj++) {
        int j = jg * 28 + jj;
        float wwv = ldf(wv, (32 + j) * 256 + d2, fm);
        sa += a_[j] * wwv; sc3 += c_[j] * wwv; sd += d_[j] * wwv;
      }
      __shared__ float ps[3][8][32];
      ps[0][jg][dsub] = sa; ps[1][jg][dsub] = sc3; ps[2][jg][dsub] = sd;
      __syncthreads();
      if (tid < 32) {
        float ra = 0.f, rc = 0.f, rd = 0.f;
        #pragma unroll
        for (int g = 0; g < 8; g++) {
          ra += ps[0][g][tid]; rc += ps[1][g][tid]; rd += ps[2][g][tid];
        }
        int d3 = v * 32 + tid;
        ws[WS_AV3 + d3] = ra;
        ws[WS_AV3 + 256 + d3] = rc;
        ws[WS_AV3 + 512 + d3] = rd + ldf(bv, d3, fm);
      }
    }
  } else if (blk < 128) {
    int fm = detect_fm_block(times);
    int mm = detect_mm_block(mask);
    int sblk = blk - 64, b = sblk >> 3, chunk = sblk & 7;
    __shared__ float hc[64], hsv[64], hst[64];
    __shared__ unsigned int hvn[64], hvx[64], htn[64], htx[64];
    if (tid < 64) {
      hc[tid] = 0.f; hsv[tid] = 0.f; hst[tid] = 0.f;
      hvn[tid] = 0xFFFFFFFFu; hvx[tid] = 0u;
      htn[tid] = 0xFFFFFFFFu; htx[tid] = 0u;
    }
    __syncthreads();
    #pragma unroll
    for (int k = 0; k < 4; k++) {
      int idx = b * SS + chunk * 1024 + k * 256 + tid;
      if (mask_at(mask, idx, mm)) {
        int f = fids[idx];
        float val = ldf(values, idx, fm), tim = ldf(times, idx, fm);
        atomicAdd(&hc[f], 1.0f);
        atomicAdd(&hsv[f], val);
        atomicAdd(&hst[f], tim);
        unsigned int vk = fkey(val), tk = fkey(tim);
        atomicMin(&hvn[f], vk); atomicMax(&hvx[f], vk);
        atomicMin(&htn[f], tk); atomicMax(&htx[f], tk);
      }
    }
    __syncthreads();
    if (tid < 64) {
      int base = WS_SP + (sblk * 64 + tid) * 8;
      ws[base + 0] = hc[tid];
      ws[base + 1] = hsv[tid];
      ws[base + 2] = hst[tid];
      ((unsigned int*)ws)[base + 3] = hvn[tid];
      ((unsigned int*)ws)[base + 4] = hvx[tid];
      ((unsigned int*)ws)[base + 5] = htn[tid];
      ((unsigned int*)ws)[base + 6] = htx[tid];
    }
  } else {
    int zblk = blk - 128;
    for (int i = zblk * 256 + tid; i < 12288; i += 8 * 256) ws[WS_BINS + i] = 0.f;
    if (zblk == 0) {
      int fm = detect_fm_block(times);
      int mmm = detect_mm_block(mask);
      if (tid == 0) { ((int*)ws)[0] = fm; ((int*)ws)[1] = mmm; }
    }
  }
}

// K2: per (b,chunk): reduce stats slices -> per-(b,v,h) affine coeffs {A,B,C,m} in LDS,
//     then one scan of 1024 elements accumulating {W, W*val, W*tim} bins; global flush.
__global__ void __launch_bounds__(256) k_accum(const void* values, const void* times,
                                               const int* fids, const void* mask,
                                               float* ws) {
  int fm = ((const int*)ws)[0], mm = ((const int*)ws)[1];
  int blk = blockIdx.x, tid = threadIdx.x;
  int b = blk >> 3, chunk = blk & 7;
  __shared__ float stv[64][8];     // cnt, mv, mt, vmn, vmx, tmn, tmx
  __shared__ float co[64 * 36];    // padded: v*36 + h*4 + {A,B,C,m}
  __shared__ float bins[64 * 25];  // padded: v*25 + h*3 + {W,WV,WT}
  if (tid < 64) {
    int v = tid;
    float c = 0.f, sv = 0.f, st = 0.f;
    unsigned int vnk = 0xFFFFFFFFu, vxk = 0u, tnk = 0xFFFFFFFFu, txk = 0u;
    #pragma unroll
    for (int sl = 0; sl < 8; sl++) {
      int base = WS_SP + ((b * 8 + sl) * 64 + v) * 8;
      c += ws[base]; sv += ws[base + 1]; st += ws[base + 2];
      unsigned int a3 = ((const unsigned int*)ws)[base + 3];
      unsigned int a4 = ((const unsigned int*)ws)[base + 4];
      unsigned int a5 = ((const unsigned int*)ws)[base + 5];
      unsigned int a6 = ((const unsigned int*)ws)[base + 6];
      vnk = min(vnk, a3); vxk = max(vxk, a4);
      tnk = min(tnk, a5); txk = max(txk, a6);
    }
    float ic = (c > 0.f) ? 1.0f / c : 0.f;
    stv[v][0] = c; stv[v][1] = sv * ic; stv[v][2] = st * ic;
    stv[v][3] = funkey(vnk); stv[v][4] = funkey(vxk);
    stv[v][5] = funkey(tnk); stv[v][6] = funkey(txk);
  }
  for (int i = tid; i < 1600; i += 256) bins[i] = 0.f;
  __syncthreads();
  for (int p = tid; p < 512; p += 256) {
    int v = p >> 3, h = p & 7;
    int base = WS_M + (v * 8 + h) * 12;
    float m00 = ws[base],     m01 = ws[base + 1], m02 = ws[base + 2];
    float m10 = ws[base + 3], m11 = ws[base + 4], m12 = ws[base + 5];
    float m20 = ws[base + 6], m21 = ws[base + 7], m22 = ws[base + 8];
    float mv = stv[v][1], mt = stv[v][2];
    float A  = m00 + mv * m10 + mt * m20;
    float Bc = m01 + mv * m11 + mt * m21;
    float Cc = m02 + mv * m12 + mt * m22;
    float mstab = A + fmaxf(Bc * stv[v][3], Bc * stv[v][4])
                    + fmaxf(Cc * stv[v][5], Cc * stv[v][6]);
    int cb = v * 36 + h * 4;
    co[cb] = A; co[cb + 1] = Bc; co[cb + 2] = Cc; co[cb + 3] = mstab;
  }
  __syncthreads();
  #pragma unroll
  for (int k = 0; k < 4; k++) {
    int idx = b * SS + chunk * 1024 + k * 256 + tid;
    if (mask_at(mask, idx, mm)) {
      int f = fids[idx];
      float val = ldf(values, idx, fm), tim = ldf(times, idx, fm);
      #pragma unroll
      for (int h = 0; h < 8; h++) {
        int cb = f * 36 + h * 4;
        float w = exp2f(co[cb] + val * co[cb + 1] + tim * co[cb + 2] - co[cb + 3]);
        int bb = f * 25 + h * 3;
        atomicAdd(&bins[bb], w);
        atomicAdd(&bins[bb + 1], w * val);
        atomicAdd(&bins[bb + 2], w * tim);
      }
    }
  }
  __syncthreads();
  for (int i = tid; i < 1536; i += 256) {
    int f = i / 24, r = i - f * 24;
    float x = bins[f * 25 + r];
    if (x != 0.f) atomicAdd(&ws[WS_BINS + b * 1536 + i], x);
  }
}

// K3: bins -> normalized per-(b,v,h) means -> ctx sum over v (empty-v handled as
//     n_empty * ctx(pos 0)) -> f@wo+bo -> relu MLP -> out[b].
__global__ void __launch_bounds__(1024) k_fin(const int* fids, const void* values,
                                              const void* times, const void* wo,
                                              const void* bo, const void* cw1,
                                              const void* cb1, const void* cw2,
                                              const void* cb2, float* ws, void* out) {
  int fm = ((const int*)ws)[0];
  int b = blockIdx.x, tid = threadIdx.x;
  __shared__ float aa[64][9], tt[64][9], ne[64];
  __shared__ float ps[4][256], cs[256], fv[256], pr[16], neg_[4];
  if (tid < 512) {
    int v = tid >> 3, h = tid & 7;
    int base = WS_BINS + b * 1536 + v * 24 + h * 3;
    float W = ws[base], WV = ws[base + 1], WT = ws[base + 2];
    float iW = (W > 0.f) ? 1.0f / W : 0.f;
    aa[v][h] = WV * iW; tt[v][h] = WT * iW;
    if (h == 0) ne[v] = (W > 0.f) ? 1.f : 0.f;
  }
  __syncthreads();
  int d = tid & 255, vg = tid >> 8, h = d >> 5;
  float accP = 0.f, accA = 0.f, accT = 0.f, accN = 0.f;
  #pragma unroll 4
  for (int k = 0; k < 16; k++) {
    int v = vg * 16 + k;
    float nef = ne[v];
    accP += nef * ws[WS_WVE + v * 256 + d];
    accA += aa[v][h];    // zero for empty v
    accT += tt[v][h];
    accN += nef;
  }
  ps[vg][d] = accP + accN * ws[WS_AV3 + 512 + d]
            + accA * ws[WS_AV3 + d] + accT * ws[WS_AV3 + 256 + d];
  if (d == 0) neg_[vg] = accN;
  __syncthreads();
  if (tid < 256) {
    float nE = 64.f - (neg_[0] + neg_[1] + neg_[2] + neg_[3]);
    float ce = 0.f;
    if (nE > 0.f) {
      int f0 = fids[b * SS];
      float v0 = ldf(values, b * SS, fm), t0 = ldf(times, b * SS, fm);
      ce = nE * (ws[WS_WVE + f0 * 256 + tid] + ws[WS_AV3 + 512 + tid]
               + v0 * ws[WS_AV3 + tid] + t0 * ws[WS_AV3 + 256 + tid]);
    }
    cs[tid] = (ps[0][tid] + ps[1][tid] + ps[2][tid] + ps[3][tid] + ce) * (1.0f / 64.0f);
  }
  __syncthreads();
  float s = 0.f;
  #pragma unroll 8
  for (int k = 0; k < 64; k++) {
    int i = vg * 64 + k;
    s += cs[i] * ldf(wo, i * 256 + d, fm);
  }
  ps[vg][d] = s;
  __syncthreads();
  if (tid < 256) fv[tid] = ps[0][tid] + ps[1][tid] + ps[2][tid] + ps[3][tid]
                         + ldf(bo, tid, fm);
  __syncthreads();
  float t2 = 0.f;
  #pragma unroll 8
  for (int k = 0; k < 64; k++) {
    int i = vg * 64 + k;
    t2 += fv[i] * ldf(cw1, i * 256 + d, fm);
  }
  ps[vg][d] = t2;
  __syncthreads();
  float p = 0.f;
  if (tid < 256) {
    float t = ps[0][tid] + ps[1][tid] + ps[2][tid] + ps[3][tid] + ldf(cb1, tid, fm);
    t = fmaxf(t, 0.f);
    p = t * ldf(cw2, tid, fm);
  }
  #pragma unroll
  for (int off = 32; off >= 1; off >>= 1) p += __shfl_xor(p, off);
  if ((tid & 63) == 0) pr[tid >> 6] = p;
  __syncthreads();
  if (tid == 0) {
    float o = ldf(cb2, 0, fm);
    #pragma unroll
    for (int wgi = 0; wgi < 16; wgi++) o += pr[wgi];
    if (fm) {
      unsigned int x = __float_as_uint(o);
      unsigned int r = (x + 0x7FFFu + ((x >> 16) & 1u)) >> 16;  // RNE
      ((unsigned short*)out)[b] = (unsigned short)r;
    } else {
      ((float*)out)[b] = o;
    }
  }
}

extern "C" void kernel_launch(void* const* d_in, const int* in_sizes, int n_in,
                              void* d_out, int out_size, void* d_ws, size_t ws_size,
                              hipStream_t stream) {
  const void* times   = d_in[0];
  const int*  fids    = (const int*)d_in[1];
  const void* values  = d_in[2];
  const void* vmask   = d_in[3];
  const void* me_w    = d_in[4];
  const void* me_b    = d_in[5];
  const void* var_emb = d_in[6];
  const void* time_w  = d_in[7];
  const void* time_b  = d_in[8];
  const void* agg_w   = d_in[9];
  const void* agg_b   = d_in[10];
  const void* wq = d_in[11]; const void* bq = d_in[12];
  const void* wk = d_in[13];
  const void* wv = d_in[15]; const void* bv = d_in[16];
  const void* wo = d_in[17]; const void* bo = d_in[18];
  const void* cw1 = d_in[19]; const void* cb1 = d_in[20];
  const void* cw2 = d_in[21]; const void* cb2 = d_in[22];
  float* ws = (float*)d_ws;

  k_front<<<136, 256, 0, stream>>>(times, values, fids, vmask,
                                   me_w, me_b, time_w, time_b, agg_w, agg_b,
                                   var_emb, wq, wk, wv, bq, bv, ws);
  k_accum<<<64, 256, 0, stream>>>(values, times, fids, vmask, ws);
  k_fin<<<8, 1024, 0, stream>>>(fids, values, times, wo, bo, cw1, cb1, cw2, cb2,
                                ws, d_out);
}

// Round 5
// 158.256 us; speedup vs baseline: 1.8430x; 1.8430x over previous
//
#include <hip/hip_runtime.h>
#include <hip/hip_bf16.h>
#include <math.h>

// Problem dims (fixed by reference)
#define BB 8
#define SS 8192
#define AGG_OUT 224   // D - DV

// ---- workspace layout (float/int32 slots, 4B each) ----
#define WS_FLAGS 0       // [0]=floatmode(1=bf16,0=f32) [1]=maskmode(0=i32,1=f32,2=bf16,3=u8)
#define WS_A     16      // a[224] : h_l[:,32+j] = val*a[j] + tim*c[j] + d[j]
#define WS_C     240
#define WS_D     464
#define WS_AQ    688     // AQ/CQ/DQ [256] each (DQ includes bq)
#define WS_CQ    944
#define WS_DQ    1200
#define WS_AK    1456    // AK/CK/DK [256] (DK includes bk)
#define WS_CK    1712
#define WS_DK    1968
#define WS_AV3   2224    // AV[256], CV[256], DV[256] (DV includes bv)
#define WS_WQE   2992    // var_emb @ wq[0:32,:]  [64*256]
#define WS_WKE   19376
#define WS_WVE   35760
#define WS_SP    52144   // [64 sblk * 64 v * 8] stats partials {cnt,sv,st,vmnK,vmxK,tmnK,tmxK,pad}
#define WS_BINS  84912   // [8b*64v*24] v*24 + h*3 + {W,WV,WT}  (zeroed in K1)

__device__ __forceinline__ float ldf(const void* p, int idx, int fm) {
  if (fm) {
    unsigned int u = ((const unsigned short*)p)[idx];
    return __uint_as_float(u << 16);
  }
  return ((const float*)p)[idx];
}

__device__ __forceinline__ bool mask_at(const void* p, int idx, int mm) {
  switch (mm) {
    case 0: return ((const int*)p)[idx] != 0;
    case 1: return ((const float*)p)[idx] != 0.0f;
    case 2: return ((const unsigned short*)p)[idx] != 0;
    default: return ((const unsigned char*)p)[idx] != 0;
  }
}

// order-preserving float<->uint key (for atomicMin/Max on LDS uints)
__device__ __forceinline__ unsigned int fkey(float f) {
  unsigned int u = __float_as_uint(f);
  return (u & 0x80000000u) ? ~u : (u | 0x80000000u);
}
__device__ __forceinline__ float funkey(unsigned int k) {
  unsigned int u = (k & 0x80000000u) ? (k ^ 0x80000000u) : ~k;
  return __uint_as_float(u);
}

__device__ __forceinline__ int detect_fm_block(const void* times) {
  __shared__ int cntR;
  int tid = threadIdx.x;
  if (tid == 0) cntR = 0;
  __syncthreads();
  const unsigned int* tw = (const unsigned int*)times;
  int local = 0;
  for (int i = tid; i < 1024; i += 256) {
    unsigned int lo = tw[i] & 0xFFFFu;
    if (lo >= 0x3800u && lo < 0x3F80u) local++;   // bf16 pattern of U(0,1)
  }
  atomicAdd(&cntR, local);
  __syncthreads();
  int r = (cntR > 512) ? 1 : 0;
  __syncthreads();
  return r;
}

__device__ __forceinline__ int detect_mm_block(const void* mask) {
  __shared__ int f01, ff32, fbf;
  int tid = threadIdx.x;
  if (tid == 0) { f01 = 1; ff32 = 1; fbf = 1; }
  __syncthreads();
  const unsigned int* mw = (const unsigned int*)mask;
  int l01 = 1, lf32 = 1, lbf = 1;
  for (int i = tid; i < 2048; i += 256) {
    unsigned int w = mw[i];
    if (w > 1u) l01 = 0;
    if (!(w == 0u || w == 0x3F800000u)) lf32 = 0;
    unsigned int h0 = w & 0xFFFFu, h1 = w >> 16;
    if (!((h0 == 0u || h0 == 0x3F80u) && (h1 == 0u || h1 == 0x3F80u))) lbf = 0;
  }
  if (!l01) atomicAnd(&f01, 0);
  if (!lf32) atomicAnd(&ff32, 0);
  if (!lbf) atomicAnd(&fbf, 0);
  __syncthreads();
  int r = f01 ? 0 : (ff32 ? 1 : (fbf ? 2 : 3));
  __syncthreads();
  return r;
}

// K1 (all blocks independent):
//   0..223   acd collapse, thread-parallel over i (1 load deep + shuffle reduce)
//   224..287 per-(b,chunk) segment stats histograms
//   288..479 embedding tables: var_emb @ w{q,k,v}[0:32,:]
//   480..487 zero BINS; blk 480 publishes flags
__global__ void __launch_bounds__(256) k_front(const void* times, const void* values,
                                               const int* fids, const void* mask,
                                               const void* me_w, const void* me_b,
                                               const void* time_w, const void* time_b,
                                               const void* agg_w, const void* agg_b,
                                               const void* var_emb, const void* wq,
                                               const void* wk, const void* wv,
                                               float* ws) {
  int blk = blockIdx.x, tid = threadIdx.x;
  if (blk < 224) {
    int fm = detect_fm_block(times);
    int j = blk, i = tid;
    float w0 = ldf(agg_w, i * AGG_OUT + j, fm);
    float w1 = ldf(agg_w, (256 + i) * AGG_OUT + j, fm);
    float sa = ldf(me_w, i, fm) * w0;
    float sc = ldf(time_w, i, fm) * w1;
    float sd = ldf(me_b, i, fm) * w0 + ldf(time_b, i, fm) * w1;
    #pragma unroll
    for (int off = 32; off >= 1; off >>= 1) {
      sa += __shfl_xor(sa, off);
      sc += __shfl_xor(sc, off);
      sd += __shfl_xor(sd, off);
    }
    __shared__ float r[3][4];
    int wid = i >> 6;
    if ((i & 63) == 0) { r[0][wid] = sa; r[1][wid] = sc; r[2][wid] = sd; }
    __syncthreads();
    if (i == 0) {
      ws[WS_A + j] = r[0][0] + r[0][1] + r[0][2] + r[0][3];
      ws[WS_C + j] = r[1][0] + r[1][1] + r[1][2] + r[1][3];
      ws[WS_D + j] = r[2][0] + r[2][1] + r[2][2] + r[2][3] + ldf(agg_b, j, fm);
    }
  } else if (blk < 288) {
    int fm = detect_fm_block(times);
    int mm = detect_mm_block(mask);
    int sblk = blk - 224, b = sblk >> 3, chunk = sblk & 7;
    __shared__ float hc[64], hsv[64], hst[64];
    __shared__ unsigned int hvn[64], hvx[64], htn[64], htx[64];
    if (tid < 64) {
      hc[tid] = 0.f; hsv[tid] = 0.f; hst[tid] = 0.f;
      hvn[tid] = 0xFFFFFFFFu; hvx[tid] = 0u;
      htn[tid] = 0xFFFFFFFFu; htx[tid] = 0u;
    }
    __syncthreads();
    #pragma unroll
    for (int k = 0; k < 4; k++) {
      int idx = b * SS + chunk * 1024 + k * 256 + tid;
      if (mask_at(mask, idx, mm)) {
        int f = fids[idx];
        float val = ldf(values, idx, fm), tim = ldf(times, idx, fm);
        atomicAdd(&hc[f], 1.0f);
        atomicAdd(&hsv[f], val);
        atomicAdd(&hst[f], tim);
        unsigned int vk = fkey(val), tk = fkey(tim);
        atomicMin(&hvn[f], vk); atomicMax(&hvx[f], vk);
        atomicMin(&htn[f], tk); atomicMax(&htx[f], tk);
      }
    }
    __syncthreads();
    if (tid < 64) {
      int base = WS_SP + (sblk * 64 + tid) * 8;
      ws[base + 0] = hc[tid];
      ws[base + 1] = hsv[tid];
      ws[base + 2] = hst[tid];
      ((unsigned int*)ws)[base + 3] = hvn[tid];
      ((unsigned int*)ws)[base + 4] = hvx[tid];
      ((unsigned int*)ws)[base + 5] = htn[tid];
      ((unsigned int*)ws)[base + 6] = htx[tid];
    }
  } else if (blk < 480) {
    int fm = detect_fm_block(times);
    int idx = blk - 288, X = idx >> 6, v = idx & 63, d = tid;
    const void* w = (X == 0) ? wq : (X == 1) ? wk : wv;
    float s = 0.f;
    #pragma unroll 8
    for (int i = 0; i < 32; i++)
      s += ldf(var_emb, v * 32 + i, fm) * ldf(w, i * 256 + d, fm);
    int base = (X == 0) ? WS_WQE : (X == 1) ? WS_WKE : WS_WVE;
    ws[base + v * 256 + d] = s;
  } else {
    int zblk = blk - 480;
    for (int i = zblk * 256 + tid; i < 12288; i += 8 * 256) ws[WS_BINS + i] = 0.f;
    if (zblk == 0) {
      int fm = detect_fm_block(times);
      int mmm = detect_mm_block(mask);
      if (tid == 0) { ((int*)ws)[0] = fm; ((int*)ws)[1] = mmm; }
    }
  }
}

// K2: fold a/c/d through wq/wk/wv -> AQ/CQ/DQ, AK/CK/DK, AV/CV/DV (biases folded in).
// 24 blocks = 3 matrices x 8 d-groups; thread-parallel 32d x 8jg, LDS-held acd.
__global__ void __launch_bounds__(256) k_fold(const void* wq, const void* wk,
                                              const void* wv, const void* bq,
                                              const void* bk, const void* bv,
                                              float* ws) {
  int fm = ((const int*)ws)[0];
  int blk = blockIdx.x, tid = threadIdx.x;
  int X = blk >> 3, dg = blk & 7;
  const void* w = (X == 0) ? wq : (X == 1) ? wk : wv;
  __shared__ float sha[224], shc[224], shd[224];
  if (tid < 224) {
    sha[tid] = ws[WS_A + tid];
    shc[tid] = ws[WS_C + tid];
    shd[tid] = ws[WS_D + tid];
  }
  __syncthreads();
  int dsub = tid & 31, jg = tid >> 5;        // 32 d x 8 j-groups, 8*28 = 224
  int d = dg * 32 + dsub;
  float sa = 0.f, sc = 0.f, sd = 0.f;
  #pragma unroll 4
  for (int jj = 0; jj < 28; jj++) {
    int j = jg * 28 + jj;
    float ww = ldf(w, (32 + j) * 256 + d, fm);
    sa += sha[j] * ww; sc += shc[j] * ww; sd += shd[j] * ww;
  }
  __shared__ float ps[3][8][32];
  ps[0][jg][dsub] = sa; ps[1][jg][dsub] = sc; ps[2][jg][dsub] = sd;
  __syncthreads();
  if (tid < 32) {
    float ra = 0.f, rc = 0.f, rd = 0.f;
    #pragma unroll
    for (int g = 0; g < 8; g++) {
      ra += ps[0][g][tid]; rc += ps[1][g][tid]; rd += ps[2][g][tid];
    }
    int dd = dg * 32 + tid;
    if (X == 0) rd += ldf(bq, dd, fm);
    if (X == 1) rd += ldf(bk, dd, fm);
    if (X == 2) rd += ldf(bv, dd, fm);
    int base = (X == 0) ? WS_AQ : (X == 1) ? WS_AK : WS_AV3;
    ws[base + dd] = ra;
    ws[base + 256 + dd] = rc;
    ws[base + 512 + dd] = rd;
  }
}

// K3: per (b,chunk): reduce stats slices -> per-(v,h) affine coeffs {A,B,C,m}
//     (direct 32-dim dots over L2-resident q0/k0; log2e-prescaled), then one scan
//     of 1024 elements accumulating {W, W*val, W*tim} bins; global flush.
__global__ void __launch_bounds__(256) k_accum(const void* values, const void* times,
                                               const int* fids, const void* mask,
                                               float* ws) {
  int fm = ((const int*)ws)[0], mm = ((const int*)ws)[1];
  int blk = blockIdx.x, tid = threadIdx.x;
  int b = blk >> 3, chunk = blk & 7;
  __shared__ float stv[64][8];     // cnt, mv, mt, vmn, vmx, tmn, tmx
  __shared__ float sF[6][256];     // AQ,CQ,DQ,AK,CK,DK
  __shared__ float co[64 * 36];    // padded: v*36 + h*4 + {A,B,C,m}
  __shared__ float bins[64 * 25];  // padded: v*25 + h*3 + {W,WV,WT}
  sF[0][tid] = ws[WS_AQ + tid];
  sF[1][tid] = ws[WS_CQ + tid];
  sF[2][tid] = ws[WS_DQ + tid];
  sF[3][tid] = ws[WS_AK + tid];
  sF[4][tid] = ws[WS_CK + tid];
  sF[5][tid] = ws[WS_DK + tid];
  if (tid < 64) {
    int v = tid;
    float c = 0.f, sv = 0.f, st = 0.f;
    unsigned int vnk = 0xFFFFFFFFu, vxk = 0u, tnk = 0xFFFFFFFFu, txk = 0u;
    #pragma unroll
    for (int sl = 0; sl < 8; sl++) {
      int base = WS_SP + ((b * 8 + sl) * 64 + v) * 8;
      c += ws[base]; sv += ws[base + 1]; st += ws[base + 2];
      unsigned int a3 = ((const unsigned int*)ws)[base + 3];
      unsigned int a4 = ((const unsigned int*)ws)[base + 4];
      unsigned int a5 = ((const unsigned int*)ws)[base + 5];
      unsigned int a6 = ((const unsigned int*)ws)[base + 6];
      vnk = min(vnk, a3); vxk = max(vxk, a4);
      tnk = min(tnk, a5); txk = max(txk, a6);
    }
    float ic = (c > 0.f) ? 1.0f / c : 0.f;
    stv[v][0] = c; stv[v][1] = sv * ic; stv[v][2] = st * ic;
    stv[v][3] = funkey(vnk); stv[v][4] = funkey(vxk);
    stv[v][5] = funkey(tnk); stv[v][6] = funkey(txk);
  }
  for (int i = tid; i < 1600; i += 256) bins[i] = 0.f;
  __syncthreads();
  const float sc2 = 0.17677669529663687f * 1.4426950408889634f;  // 1/sqrt(32)*log2e
  #pragma unroll
  for (int pp = 0; pp < 2; pp++) {
    int p = pp * 256 + tid;
    int v = p >> 3, h = p & 7;
    float A = 0.f, Bc = 0.f, Cc = 0.f;
    float mv = stv[v][1], mt = stv[v][2];
    #pragma unroll 8
    for (int i = 0; i < 32; i++) {
      int d = h * 32 + i;
      float wqe = ws[WS_WQE + v * 256 + d];
      float wke = ws[WS_WKE + v * 256 + d];
      float q = wqe + sF[2][d] + mv * sF[0][d] + mt * sF[1][d];
      float k0 = wke + sF[5][d];
      A += q * k0; Bc += q * sF[3][d]; Cc += q * sF[4][d];
    }
    A *= sc2; Bc *= sc2; Cc *= sc2;
    float mstab = A + fmaxf(Bc * stv[v][3], Bc * stv[v][4])
                    + fmaxf(Cc * stv[v][5], Cc * stv[v][6]);
    int cb = v * 36 + h * 4;
    bool live = (stv[v][0] > 0.f);
    co[cb] = live ? A : 0.f;
    co[cb + 1] = live ? Bc : 0.f;
    co[cb + 2] = live ? Cc : 0.f;
    co[cb + 3] = live ? mstab : 0.f;
  }
  __syncthreads();
  #pragma unroll
  for (int k = 0; k < 4; k++) {
    int idx = b * SS + chunk * 1024 + k * 256 + tid;
    if (mask_at(mask, idx, mm)) {
      int f = fids[idx];
      float val = ldf(values, idx, fm), tim = ldf(times, idx, fm);
      #pragma unroll
      for (int h = 0; h < 8; h++) {
        int cb = f * 36 + h * 4;
        float w = exp2f(co[cb] + val * co[cb + 1] + tim * co[cb + 2] - co[cb + 3]);
        int bb = f * 25 + h * 3;
        atomicAdd(&bins[bb], w);
        atomicAdd(&bins[bb + 1], w * val);
        atomicAdd(&bins[bb + 2], w * tim);
      }
    }
  }
  __syncthreads();
  for (int i = tid; i < 1536; i += 256) {
    int f = i / 24, r = i - f * 24;
    float x = bins[f * 25 + r];
    if (x != 0.f) atomicAdd(&ws[WS_BINS + b * 1536 + i], x);
  }
}

// K4: bins -> normalized per-(b,v,h) means -> ctx sum over v (empty-v handled as
//     n_empty * ctx(pos 0)) -> f@wo+bo -> relu MLP -> out[b].
__global__ void __launch_bounds__(1024) k_fin(const int* fids, const void* values,
                                              const void* times, const void* wo,
                                              const void* bo, const void* cw1,
                                              const void* cb1, const void* cw2,
                                              const void* cb2, float* ws, void* out) {
  int fm = ((const int*)ws)[0];
  int b = blockIdx.x, tid = threadIdx.x;
  __shared__ float aa[64][9], tt[64][9], ne[64];
  __shared__ float ps[4][256], cs[256], fv[256], pr[16], neg_[4];
  if (tid < 512) {
    int v = tid >> 3, h = tid & 7;
    int base = WS_BINS + b * 1536 + v * 24 + h * 3;
    float W = ws[base], WV = ws[base + 1], WT = ws[base + 2];
    float iW = (W > 0.f) ? 1.0f / W : 0.f;
    aa[v][h] = WV * iW; tt[v][h] = WT * iW;
    if (h == 0) ne[v] = (W > 0.f) ? 1.f : 0.f;
  }
  __syncthreads();
  int d = tid & 255, vg = tid >> 8, h = d >> 5;
  float accP = 0.f, accA = 0.f, accT = 0.f, accN = 0.f;
  #pragma unroll 4
  for (int k = 0; k < 16; k++) {
    int v = vg * 16 + k;
    float nef = ne[v];
    accP += nef * ws[WS_WVE + v * 256 + d];
    accA += aa[v][h];    // zero for empty v
    accT += tt[v][h];
    accN += nef;
  }
  ps[vg][d] = accP + accN * ws[WS_AV3 + 512 + d]
            + accA * ws[WS_AV3 + d] + accT * ws[WS_AV3 + 256 + d];
  if (d == 0) neg_[vg] = accN;
  __syncthreads();
  if (tid < 256) {
    float nE = 64.f - (neg_[0] + neg_[1] + neg_[2] + neg_[3]);
    float ce = 0.f;
    if (nE > 0.f) {
      int f0 = fids[b * SS];
      float v0 = ldf(values, b * SS, fm), t0 = ldf(times, b * SS, fm);
      ce = nE * (ws[WS_WVE + f0 * 256 + tid] + ws[WS_AV3 + 512 + tid]
               + v0 * ws[WS_AV3 + tid] + t0 * ws[WS_AV3 + 256 + tid]);
    }
    cs[tid] = (ps[0][tid] + ps[1][tid] + ps[2][tid] + ps[3][tid] + ce) * (1.0f / 64.0f);
  }
  __syncthreads();
  float s = 0.f;
  #pragma unroll 8
  for (int k = 0; k < 64; k++) {
    int i = vg * 64 + k;
    s += cs[i] * ldf(wo, i * 256 + d, fm);
  }
  ps[vg][d] = s;
  __syncthreads();
  if (tid < 256) fv[tid] = ps[0][tid] + ps[1][tid] + ps[2][tid] + ps[3][tid]
                         + ldf(bo, tid, fm);
  __syncthreads();
  float t2 = 0.f;
  #pragma unroll 8
  for (int k = 0; k < 64; k++) {
    int i = vg * 64 + k;
    t2 += fv[i] * ldf(cw1, i * 256 + d, fm);
  }
  ps[vg][d] = t2;
  __syncthreads();
  float p = 0.f;
  if (tid < 256) {
    float t = ps[0][tid] + ps[1][tid] + ps[2][tid] + ps[3][tid] + ldf(cb1, tid, fm);
    t = fmaxf(t, 0.f);
    p = t * ldf(cw2, tid, fm);
  }
  #pragma unroll
  for (int off = 32; off >= 1; off >>= 1) p += __shfl_xor(p, off);
  if ((tid & 63) == 0) pr[tid >> 6] = p;
  __syncthreads();
  if (tid == 0) {
    float o = ldf(cb2, 0, fm);
    #pragma unroll
    for (int wgi = 0; wgi < 16; wgi++) o += pr[wgi];
    if (fm) {
      unsigned int x = __float_as_uint(o);
      unsigned int r = (x + 0x7FFFu + ((x >> 16) & 1u)) >> 16;  // RNE
      ((unsigned short*)out)[b] = (unsigned short)r;
    } else {
      ((float*)out)[b] = o;
    }
  }
}

extern "C" void kernel_launch(void* const* d_in, const int* in_sizes, int n_in,
                              void* d_out, int out_size, void* d_ws, size_t ws_size,
                              hipStream_t stream) {
  const void* times   = d_in[0];
  const int*  fids    = (const int*)d_in[1];
  const void* values  = d_in[2];
  const void* vmask   = d_in[3];
  const void* me_w    = d_in[4];
  const void* me_b    = d_in[5];
  const void* var_emb = d_in[6];
  const void* time_w  = d_in[7];
  const void* time_b  = d_in[8];
  const void* agg_w   = d_in[9];
  const void* agg_b   = d_in[10];
  const void* wq = d_in[11]; const void* bq = d_in[12];
  const void* wk = d_in[13]; const void* bk = d_in[14];
  const void* wv = d_in[15]; const void* bv = d_in[16];
  const void* wo = d_in[17]; const void* bo = d_in[18];
  const void* cw1 = d_in[19]; const void* cb1 = d_in[20];
  const void* cw2 = d_in[21]; const void* cb2 = d_in[22];
  float* ws = (float*)d_ws;

  k_front<<<488, 256, 0, stream>>>(times, values, fids, vmask,
                                   me_w, me_b, time_w, time_b, agg_w, agg_b,
                                   var_emb, wq, wk, wv, ws);
  k_fold<<<24, 256, 0, stream>>>(wq, wk, wv, bq, bk, bv, ws);
  k_accum<<<64, 256, 0, stream>>>(values, times, fids, vmask, ws);
  k_fin<<<8, 1024, 0, stream>>>(fids, values, times, wo, bo, cw1, cb1, cw2, cb2,
                                ws, d_out);
}